// Round 9
// baseline (413.998 us; speedup 1.0000x reference)
//
#include <hip/hip_runtime.h>
#include <hip/hip_fp16.h>
#include <stdint.h>
#include <stddef.h>

#define FIN 256
#define NH  64
#define CAP 64     // max degree: E/N=16 avg Poisson, P(deg>64) ~ 1e-19
#define NBKT 196   // ceil(50000/256) dst buckets of 256 nodes
#define BCAP 4608  // bucket region capacity: mean 4082, sd 64, +8 sigma
#define LBUF 32    // LDS staging records per bucket (51 KB -> 3 blocks/CU)
#define ROUND 4096 // edges staged per block-synchronous round
#define EPB 4096   // edges per block in pass 1 (= 1 round -> 588 blocks)

typedef unsigned int uint;
typedef __attribute__((ext_vector_type(8))) short bf16x8;  // MFMA A/B frag (4 VGPRs)
typedef __attribute__((ext_vector_type(4))) float f32x4;   // MFMA C/D frag

union ABfrag { uint u[4]; bf16x8 v; };

// pack two fp32 -> bf16 pair (RNE), low = first element
__device__ __forceinline__ uint pack_bf16x2(float a, float b) {
  uint ua = __float_as_uint(a);
  uint ub = __float_as_uint(b);
  uint ra = (ua + 0x7FFFu + ((ua >> 16) & 1u)) >> 16;
  uint rb = (ub + 0x7FFFu + ((ub >> 16) & 1u)) & 0xFFFF0000u;
  return ra | rb;
}

__device__ __forceinline__ float rec_w(uint r) {
  return __half2float(__ushort_as_half((unsigned short)(r >> 16)));
}

// ---------------- W1 -> MFMA B-frag swizzle + zero bucket counters ----------
// wsw[v][ks(8)][nt(4)][lane(64)][4 uints]; elem j = W1[ks*32+(lane>>4)*8+j][nt*16+(lane&15)]
__global__ __launch_bounds__(256) void k_wprep(
    const float* __restrict__ W10, const float* __restrict__ W11, const float* __restrict__ W12,
    uint* __restrict__ wsw, int* __restrict__ bcnt) {
  int v = blockIdx.x;
  const float* __restrict__ W = v == 0 ? W10 : (v == 1 ? W11 : W12);
  uint4* __restrict__ o = (uint4*)(wsw + v * 8192);
  for (int t = threadIdx.x; t < 2048; t += 256) {
    int lane = t & 63;
    int nt = (t >> 6) & 3;
    int ks = t >> 8;
    int kb = ks * 32 + (lane >> 4) * 8;
    int col = nt * 16 + (lane & 15);
    uint4 r;
    r.x = pack_bf16x2(W[(kb + 0) * NH + col], W[(kb + 1) * NH + col]);
    r.y = pack_bf16x2(W[(kb + 2) * NH + col], W[(kb + 3) * NH + col]);
    r.z = pack_bf16x2(W[(kb + 4) * NH + col], W[(kb + 5) * NH + col]);
    r.w = pack_bf16x2(W[(kb + 6) * NH + col], W[(kb + 7) * NH + col]);
    o[t] = r;
  }
  if (threadIdx.x < NBKT) bcnt[v * NBKT + threadIdx.x] = 0;
}

// ---------------- pass 1: bucket edges by dst>>8 via LDS staging ------------
// stage: 2 edges/thread vector loads; flush: wave-cooperative (parallel copy)
__global__ __launch_bounds__(256) void k_p1(
    const int* __restrict__ ei0, const int* __restrict__ ei1, const int* __restrict__ ei2,
    const float* __restrict__ ew0, const float* __restrict__ ew1, const float* __restrict__ ew2,
    int* __restrict__ bcnt, uint2* __restrict__ bbuf, int E) {
  int v = blockIdx.y;
  const int*   ei = v == 0 ? ei0 : (v == 1 ? ei1 : ei2);
  const float* ew = v == 0 ? ew0 : (v == 1 ? ew1 : ew2);
  int* __restrict__ bc = bcnt + v * NBKT;
  uint2* __restrict__ bb = bbuf + (size_t)v * NBKT * BCAP;
  __shared__ uint2 buf[NBKT * LBUF];   // 50.2 KB -> 3 blocks/CU
  __shared__ int ticket[NBKT];
  int tid = threadIdx.x;
  int lane = tid & 63;
  int wid = tid >> 6;
  int base = blockIdx.x * EPB;
  int end = min(base + EPB, E);   // end-base always even (E even, EPB even)
  for (int rbase = base; rbase < end; rbase += ROUND) {
    for (int b = tid; b < NBKT; b += 256) ticket[b] = 0;
    __syncthreads();
    // stage: 2 edges per thread (vectorized reads)
    for (int i = 0; i < ROUND; i += 512) {
      int e = rbase + i + tid * 2;
      if (e < end) {
        int2   s2 = *(const int2*)(ei + e);
        int2   d2 = *(const int2*)(ei + E + e);
        float2 w2 = *(const float2*)(ew + e);
#pragma unroll
        for (int q = 0; q < 2; q++) {
          int s = q ? s2.y : s2.x;
          int d = q ? d2.y : d2.x;
          float w = q ? w2.y : w2.x;
          int bkt = d >> 8;
          uint2 rec;
          rec.x = (uint)s | ((uint)(d & 255) << 16);
          rec.y = __float_as_uint(w);
          int t = atomicAdd(&ticket[bkt], 1);
          if (t < LBUF) {
            buf[bkt * LBUF + t] = rec;
          } else {
            int gp = atomicAdd(&bc[bkt], 1);
            if (gp < BCAP) bb[(size_t)bkt * BCAP + gp] = rec;
          }
        }
      }
    }
    __syncthreads();
    // flush: one bucket per wave, lanes copy records in parallel
    for (int b = wid; b < NBKT; b += 4) {
      int c = min(ticket[b], LBUF);   // wave-uniform
      if (c == 0) continue;
      int gbase = 0;
      if (lane == 0) gbase = atomicAdd(&bc[b], c);
      gbase = __shfl(gbase, 0, 64);
      if (lane < c) {
        int gp = gbase + lane;
        if (gp < BCAP) bb[(size_t)b * BCAP + gp] = buf[b * LBUF + lane];
      }
    }
    __syncthreads();
  }
}

// ---------------- pass 2: bucket -> CSR rows (8-padded) + cnt + dinv --------
__global__ __launch_bounds__(256) void k_p2(
    const int* __restrict__ bcnt, const uint2* __restrict__ bbuf,
    int* __restrict__ cnt, uint* __restrict__ csr,
    float* __restrict__ dinv1, float* __restrict__ dinv2, int N) {
  int bkt = blockIdx.x;
  int v = blockIdx.y;
  int tid = threadIdx.x;
  __shared__ int lcnt[256];
  __shared__ float lsum[256];
  lcnt[tid] = 0;
  lsum[tid] = 0.f;
  __syncthreads();
  int m = min(bcnt[v * NBKT + bkt], BCAP);
  const uint2* __restrict__ bb = bbuf + ((size_t)v * NBKT + bkt) * BCAP;
  int nb = bkt << 8;
  int vN = v * N;
  for (int i = tid; i < m; i += 256) {
    uint2 rec = bb[i];
    int src = rec.x & 0xFFFFu;
    int dl = (rec.x >> 16) & 0xFFu;
    float w = __uint_as_float(rec.y);
    int pos = atomicAdd(&lcnt[dl], 1);
    uint r4 = (uint)src | ((uint)__half_as_ushort(__float2half_rn(w)) << 16);
    if (pos < CAP) csr[((size_t)(vN + nb + dl)) * CAP + pos] = r4;
    atomicAdd(&lsum[dl], w);
  }
  __syncthreads();
  int node = nb + tid;
  if (node < N) {
    int deg = min(lcnt[tid], CAP);
    int dpad = min((deg + 7) & ~7, CAP);
    uint* __restrict__ row = csr + (size_t)(vN + node) * CAP;
    for (int i = deg; i < dpad; i++) row[i] = 0u;  // src=0, w=+0 (inert in conv1)
    cnt[vN + node] = deg;
    dinv1[vN + node] = rsqrtf(1.0f + lsum[tid]);
    dinv2[vN + node] = rsqrtf((float)(deg + 1));
  }
}

// ---------------- GEMM1 via MFMA, 3 branches fused (x read once) ------------
__global__ __launch_bounds__(256) void k_gemm1m(
    const float* __restrict__ x, const uint* __restrict__ wsw,
    const float* __restrict__ dinv1, uint* __restrict__ xwb, int N) {
  __shared__ float sc_all[4 * 16 * 64];  // 16 KB epilogue scratch (per-wave 4 KB)
  int wave = threadIdx.x >> 6, lane = threadIdx.x & 63;
  int n0 = blockIdx.x * 64 + wave * 16;
  int m = lane & 15, kq = lane >> 4;  // A: node m, k-group kq
  int arow = min(n0 + m, N - 1);
  const float* __restrict__ xr = x + (size_t)arow * FIN + kq * 8;
  ABfrag af[8];
#pragma unroll
  for (int ks = 0; ks < 8; ks++) {
    float4 a0 = *(const float4*)(xr + ks * 32);
    float4 a1 = *(const float4*)(xr + ks * 32 + 4);
    af[ks].u[0] = pack_bf16x2(a0.x, a0.y);
    af[ks].u[1] = pack_bf16x2(a0.z, a0.w);
    af[ks].u[2] = pack_bf16x2(a1.x, a1.y);
    af[ks].u[3] = pack_bf16x2(a1.z, a1.w);
  }
  float* sc = &sc_all[wave * 1024];  // 16x64 fp32 per wave
  int row2 = lane >> 2, cg = lane & 3;
  int node = n0 + row2;
#pragma unroll
  for (int v = 0; v < 3; v++) {
    int vN = v * N;
    f32x4 acc[4];
#pragma unroll
    for (int nt = 0; nt < 4; nt++) acc[nt] = (f32x4){0.f, 0.f, 0.f, 0.f};
    const uint* __restrict__ wv = wsw + v * 8192;
#pragma unroll
    for (int ks = 0; ks < 8; ks++) {
#pragma unroll
      for (int nt = 0; nt < 4; nt++) {
        ABfrag b;
        *(uint4*)b.u = *(const uint4*)&wv[(ks * 4 + nt) * 256 + lane * 4];
        acc[nt] = __builtin_amdgcn_mfma_f32_16x16x32_bf16(af[ks].v, b.v, acc[nt], 0, 0, 0);
      }
    }
    __syncthreads();  // epilogue scratch reuse boundary (prev v's reads done)
#pragma unroll
    for (int reg = 0; reg < 4; reg++) {
      int row = kq * 4 + reg;            // C/D: row=(lane>>4)*4+reg, col=lane&15
      float d1 = dinv1[vN + min(n0 + row, N - 1)];
#pragma unroll
      for (int nt = 0; nt < 4; nt++)
        sc[row * 64 + nt * 16 + m] = acc[nt][reg] * d1;
    }
    __syncthreads();
    const float4* sr = (const float4*)&sc[row2 * 64 + cg * 16];
    float4 c0 = sr[0], c1 = sr[1], c2 = sr[2], c3 = sr[3];
    uint4 o0, o1;
    o0.x = pack_bf16x2(c0.x, c0.y); o0.y = pack_bf16x2(c0.z, c0.w);
    o0.z = pack_bf16x2(c1.x, c1.y); o0.w = pack_bf16x2(c1.z, c1.w);
    o1.x = pack_bf16x2(c2.x, c2.y); o1.y = pack_bf16x2(c2.z, c2.w);
    o1.z = pack_bf16x2(c3.x, c3.y); o1.w = pack_bf16x2(c3.z, c3.w);
    if (node < N) {
      uint4* __restrict__ dst = (uint4*)(xwb + ((size_t)vN + node) * 32 + cg * 8);
      dst[0] = o0;
      dst[1] = o1;
    }
  }
}

// ---------------- conv1 pull: 2 nodes/wave, uniform 8-wide loop -------------
__global__ __launch_bounds__(256) void k_conv1(
    const uint* __restrict__ xwb, const uint* __restrict__ csr,
    const int* __restrict__ cnt,
    const float* __restrict__ dinv1, const float* __restrict__ dinv2,
    const float* __restrict__ b10, const float* __restrict__ b11, const float* __restrict__ b12,
    const float* __restrict__ W20, const float* __restrict__ W21, const float* __restrict__ W22,
    float* __restrict__ outf, float* __restrict__ g, int N) {
  int gt = blockIdx.x * 256 + threadIdx.x;
  int sub = gt & 31;
  int n = gt >> 5;
  if (n >= N) return;
  const float* b1s[3] = {b10, b11, b12};
  const float* W2s[3] = {W20, W21, W22};
  float fsum0 = 0.f, fsum1 = 0.f;
#pragma unroll
  for (int v = 0; v < 3; v++) {
    int vN = v * N;
    int nv = vN + n;
    const uint* __restrict__ row = csr + (size_t)nv * CAP;  // 256B-aligned
    int dpad = (cnt[nv] + 7) & ~7;   // rows zero-padded to multiple of 8 in p2
    float acc0 = 0.f, acc1 = 0.f;
    for (int i = 0; i < dpad; i += 8) {
      uint4 ra = *(const uint4*)(row + i);      // 16B-aligned
      uint4 rb = *(const uint4*)(row + i + 4);
      uint p0 = xwb[(size_t)(vN + (ra.x & 0xFFFFu)) * 32 + sub];
      uint p1 = xwb[(size_t)(vN + (ra.y & 0xFFFFu)) * 32 + sub];
      uint p2 = xwb[(size_t)(vN + (ra.z & 0xFFFFu)) * 32 + sub];
      uint p3 = xwb[(size_t)(vN + (ra.w & 0xFFFFu)) * 32 + sub];
      uint p4 = xwb[(size_t)(vN + (rb.x & 0xFFFFu)) * 32 + sub];
      uint p5 = xwb[(size_t)(vN + (rb.y & 0xFFFFu)) * 32 + sub];
      uint p6 = xwb[(size_t)(vN + (rb.z & 0xFFFFu)) * 32 + sub];
      uint p7 = xwb[(size_t)(vN + (rb.w & 0xFFFFu)) * 32 + sub];
      float w0 = rec_w(ra.x), w1 = rec_w(ra.y), w2 = rec_w(ra.z), w3 = rec_w(ra.w);
      float w4 = rec_w(rb.x), w5 = rec_w(rb.y), w6 = rec_w(rb.z), w7 = rec_w(rb.w);
      acc0 += w0 * __uint_as_float(p0 << 16);
      acc1 += w0 * __uint_as_float(p0 & 0xFFFF0000u);
      acc0 += w1 * __uint_as_float(p1 << 16);
      acc1 += w1 * __uint_as_float(p1 & 0xFFFF0000u);
      acc0 += w2 * __uint_as_float(p2 << 16);
      acc1 += w2 * __uint_as_float(p2 & 0xFFFF0000u);
      acc0 += w3 * __uint_as_float(p3 << 16);
      acc1 += w3 * __uint_as_float(p3 & 0xFFFF0000u);
      acc0 += w4 * __uint_as_float(p4 << 16);
      acc1 += w4 * __uint_as_float(p4 & 0xFFFF0000u);
      acc0 += w5 * __uint_as_float(p5 << 16);
      acc1 += w5 * __uint_as_float(p5 & 0xFFFF0000u);
      acc0 += w6 * __uint_as_float(p6 << 16);
      acc1 += w6 * __uint_as_float(p6 & 0xFFFF0000u);
      acc0 += w7 * __uint_as_float(p7 << 16);
      acc1 += w7 * __uint_as_float(p7 & 0xFFFF0000u);
    }
    uint ps = xwb[(size_t)nv * 32 + sub];  // self loop
    acc0 += __uint_as_float(ps << 16);
    acc1 += __uint_as_float(ps & 0xFFFF0000u);
    float d1 = dinv1[nv];
    float2 bb = ((const float2*)b1s[v])[sub];
    float h0 = fmaxf(d1 * acc0 + bb.x, 0.f);
    float h1 = fmaxf(d1 * acc1 + bb.y, 0.f);
    fsum0 += h0;
    fsum1 += h1;
    float2 ww = ((const float2*)W2s[v])[sub];
    float p = h0 * ww.x + h1 * ww.y;
#pragma unroll
    for (int off = 16; off > 0; off >>= 1) p += __shfl_down(p, off, 32);
    if (sub == 0) g[nv] = dinv2[nv] * p;
  }
  float2 fo;
  fo.x = fsum0;
  fo.y = fsum1;
  ((float2*)(outf + (size_t)n * NH))[sub] = fo;
}

// ---------------- conv2 pull: 16 lanes/node (true deg — ignores pads) -------
__global__ __launch_bounds__(256) void k_conv2(
    const uint* __restrict__ csr, const int* __restrict__ cnt,
    const float* __restrict__ dinv2, const float* __restrict__ g,
    const float* __restrict__ b20, const float* __restrict__ b21, const float* __restrict__ b22,
    float* __restrict__ outx, int N) {
  int gt = blockIdx.x * 256 + threadIdx.x;
  int l = gt & 15;
  int n = gt >> 4;
  if (n >= N) return;
  float tot = 0.f;
#pragma unroll
  for (int v = 0; v < 3; v++) {
    int vN = v * N;
    int nv = vN + n;
    const uint* __restrict__ row = csr + (size_t)nv * CAP;
    int deg = cnt[nv];
    float acc = 0.f;
    for (int i = l; i < deg; i += 16) acc += g[vN + (row[i] & 0xFFFFu)];
#pragma unroll
    for (int off = 1; off < 16; off <<= 1) acc += __shfl_xor(acc, off, 16);
    tot += dinv2[nv] * (acc + g[nv]);
  }
  if (l == 0) outx[n] = tot + b20[0] + b21[0] + b22[0];
}

extern "C" void kernel_launch(void* const* d_in, const int* in_sizes, int n_in,
                              void* d_out, int out_size, void* d_ws, size_t ws_size,
                              hipStream_t stream) {
  const float* x   = (const float*)d_in[0];
  const int*   ei0 = (const int*)d_in[1];
  const int*   ei1 = (const int*)d_in[2];
  const int*   ei2 = (const int*)d_in[3];
  const float* ew0 = (const float*)d_in[4];
  const float* ew1 = (const float*)d_in[5];
  const float* ew2 = (const float*)d_in[6];
  const float* W10 = (const float*)d_in[7];
  const float* b10 = (const float*)d_in[8];
  const float* W20 = (const float*)d_in[9];
  const float* b20 = (const float*)d_in[10];
  const float* W11 = (const float*)d_in[11];
  const float* b11 = (const float*)d_in[12];
  const float* W21 = (const float*)d_in[13];
  const float* b21 = (const float*)d_in[14];
  const float* W12 = (const float*)d_in[15];
  const float* b12 = (const float*)d_in[16];
  const float* W22 = (const float*)d_in[17];
  const float* b22 = (const float*)d_in[18];

  const int N = in_sizes[0] / FIN;  // 50000
  const int E = in_sizes[1] / 2;    // 800000
  const int n3 = 3 * N;

  char* p = (char*)d_ws;
  auto alloc = [&](size_t bytes) -> char* {
    char* r = p;
    p += (bytes + 255) & ~(size_t)255;
    return r;
  };
  // bbuf (pass1/2) and xwb (gemm1/conv1) are disjoint in time -> alias
  size_t xwb_bytes  = (size_t)n3 * 32 * sizeof(uint);               // 19.2 MB
  size_t bbuf_bytes = (size_t)3 * NBKT * BCAP * sizeof(uint2);      // 21.7 MB
  char*  shared_rgn = alloc(xwb_bytes > bbuf_bytes ? xwb_bytes : bbuf_bytes);
  uint*  xwb   = (uint*) shared_rgn;
  uint2* bbuf  = (uint2*)shared_rgn;
  uint*  csr   = (uint*) alloc((size_t)n3 * CAP * sizeof(uint));    // 38.4 MB
  uint*  wsw   = (uint*) alloc((size_t)3 * 8192 * sizeof(uint));    // 98 KB
  int*   bcnt  = (int*)  alloc((size_t)3 * NBKT * sizeof(int));
  int*   cnt   = (int*)  alloc((size_t)n3 * sizeof(int));
  float* dinv1 = (float*)alloc((size_t)n3 * sizeof(float));
  float* dinv2 = (float*)alloc((size_t)n3 * sizeof(float));
  float* g     = (float*)alloc((size_t)n3 * sizeof(float));
  (void)ws_size;

  float* outx = (float*)d_out;        // [N]
  float* outf = (float*)d_out + N;    // [N][64]

  k_wprep<<<dim3(3), 256, 0, stream>>>(W10, W11, W12, wsw, bcnt);
  k_p1<<<dim3((E + EPB - 1) / EPB, 3), 256, 0, stream>>>(ei0, ei1, ei2,
                                                         ew0, ew1, ew2, bcnt, bbuf, E);
  k_p2<<<dim3(NBKT, 3), 256, 0, stream>>>(bcnt, bbuf, cnt, csr, dinv1, dinv2, N);
  k_gemm1m<<<dim3((N + 63) / 64), 256, 0, stream>>>(x, wsw, dinv1, xwb, N);
  k_conv1<<<dim3((N * 32 + 255) / 256), 256, 0, stream>>>(
      xwb, csr, cnt, dinv1, dinv2, b10, b11, b12, W20, W21, W22, outf, g, N);
  k_conv2<<<dim3((N * 16 + 255) / 256), 256, 0, stream>>>(csr, cnt, dinv2, g,
                                                          b20, b21, b22, outx, N);
}

// Round 10
// 274.937 us; speedup vs baseline: 1.5058x; 1.5058x over previous
//
#include <hip/hip_runtime.h>
#include <hip/hip_fp16.h>
#include <stdint.h>
#include <stddef.h>

#define FIN 256
#define NH  64
#define CAP 64     // max degree: E/N=16 avg Poisson, P(deg>64) ~ 1e-19
#define NBKT 196   // ceil(50000/256) dst buckets of 256 nodes
#define BCAP 4608  // bucket region capacity: mean 4082, sd 64, +8 sigma
#define LBUF 32    // LDS staging records per bucket
#define LSTR 33    // padded LDS stride (odd -> banks spread across buckets)
#define ROUND 4096 // edges staged per block-synchronous round
#define EPB 4096   // edges per block in pass 1 (= 1 round -> 588 blocks)

typedef unsigned int uint;
typedef __attribute__((ext_vector_type(8))) short bf16x8;  // MFMA A/B frag (4 VGPRs)
typedef __attribute__((ext_vector_type(4))) float f32x4;   // MFMA C/D frag

union ABfrag { uint u[4]; bf16x8 v; };

// pack two fp32 -> bf16 pair (RNE), low = first element
__device__ __forceinline__ uint pack_bf16x2(float a, float b) {
  uint ua = __float_as_uint(a);
  uint ub = __float_as_uint(b);
  uint ra = (ua + 0x7FFFu + ((ua >> 16) & 1u)) >> 16;
  uint rb = (ub + 0x7FFFu + ((ub >> 16) & 1u)) & 0xFFFF0000u;
  return ra | rb;
}

__device__ __forceinline__ float rec_w(uint r) {
  return __half2float(__ushort_as_half((unsigned short)(r >> 16)));
}

// ---------------- W1 -> MFMA B-frag swizzle + zero bucket counters ----------
// wsw[v][ks(8)][nt(4)][lane(64)][4 uints]; elem j = W1[ks*32+(lane>>4)*8+j][nt*16+(lane&15)]
__global__ __launch_bounds__(256) void k_wprep(
    const float* __restrict__ W10, const float* __restrict__ W11, const float* __restrict__ W12,
    uint* __restrict__ wsw, int* __restrict__ bcnt) {
  int v = blockIdx.x;
  const float* __restrict__ W = v == 0 ? W10 : (v == 1 ? W11 : W12);
  uint4* __restrict__ o = (uint4*)(wsw + v * 8192);
  for (int t = threadIdx.x; t < 2048; t += 256) {
    int lane = t & 63;
    int nt = (t >> 6) & 3;
    int ks = t >> 8;
    int kb = ks * 32 + (lane >> 4) * 8;
    int col = nt * 16 + (lane & 15);
    uint4 r;
    r.x = pack_bf16x2(W[(kb + 0) * NH + col], W[(kb + 1) * NH + col]);
    r.y = pack_bf16x2(W[(kb + 2) * NH + col], W[(kb + 3) * NH + col]);
    r.z = pack_bf16x2(W[(kb + 4) * NH + col], W[(kb + 5) * NH + col]);
    r.w = pack_bf16x2(W[(kb + 6) * NH + col], W[(kb + 7) * NH + col]);
    o[t] = r;
  }
  if (threadIdx.x < NBKT) bcnt[v * NBKT + threadIdx.x] = 0;
}

// ---------------- pass 1: bucket edges by dst>>8 via LDS staging ------------
// stage: 1 edge/thread; flush: PER-THREAD (parallel contended atomics --
// wave-serial flush with returning atomics was a 200us regression in R9)
__global__ __launch_bounds__(256) void k_p1(
    const int* __restrict__ ei0, const int* __restrict__ ei1, const int* __restrict__ ei2,
    const float* __restrict__ ew0, const float* __restrict__ ew1, const float* __restrict__ ew2,
    int* __restrict__ bcnt, uint2* __restrict__ bbuf, int E) {
  int v = blockIdx.y;
  const int*   ei = v == 0 ? ei0 : (v == 1 ? ei1 : ei2);
  const float* ew = v == 0 ? ew0 : (v == 1 ? ew1 : ew2);
  int* __restrict__ bc = bcnt + v * NBKT;
  uint2* __restrict__ bb = bbuf + (size_t)v * NBKT * BCAP;
  __shared__ uint2 buf[NBKT * LSTR];   // 51.7 KB -> 3 blocks/CU
  __shared__ int ticket[NBKT];
  int tid = threadIdx.x;
  int base = blockIdx.x * EPB;
  int end = min(base + EPB, E);
  for (int rbase = base; rbase < end; rbase += ROUND) {
    for (int b = tid; b < NBKT; b += 256) ticket[b] = 0;
    __syncthreads();
    for (int i = 0; i < ROUND; i += 256) {
      int e = rbase + i + tid;
      if (e < end) {
        int s = ei[e];
        int d = ei[E + e];
        float w = ew[e];
        int bkt = d >> 8;
        uint2 rec;
        rec.x = (uint)s | ((uint)(d & 255) << 16);
        rec.y = __float_as_uint(w);
        int t = atomicAdd(&ticket[bkt], 1);
        if (t < LBUF) {
          buf[bkt * LSTR + t] = rec;
        } else {
          int gp = atomicAdd(&bc[bkt], 1);
          if (gp < BCAP) bb[(size_t)bkt * BCAP + gp] = rec;
        }
      }
    }
    __syncthreads();
    // flush: one thread per bucket -> all global atomics issue concurrently
    for (int b = tid; b < NBKT; b += 256) {
      int c = min(ticket[b], LBUF);
      if (c > 0) {
        int gbase = atomicAdd(&bc[b], c);
        for (int j = 0; j < c; j++) {
          int gp = gbase + j;
          if (gp < BCAP) bb[(size_t)b * BCAP + gp] = buf[b * LSTR + j];
        }
      }
    }
    __syncthreads();
  }
}

// ---------------- pass 2: bucket -> CSR rows (8-padded) + cnt + dinv --------
__global__ __launch_bounds__(256) void k_p2(
    const int* __restrict__ bcnt, const uint2* __restrict__ bbuf,
    int* __restrict__ cnt, uint* __restrict__ csr,
    float* __restrict__ dinv1, float* __restrict__ dinv2, int N) {
  int bkt = blockIdx.x;
  int v = blockIdx.y;
  int tid = threadIdx.x;
  __shared__ int lcnt[256];
  __shared__ float lsum[256];
  lcnt[tid] = 0;
  lsum[tid] = 0.f;
  __syncthreads();
  int m = min(bcnt[v * NBKT + bkt], BCAP);
  const uint2* __restrict__ bb = bbuf + ((size_t)v * NBKT + bkt) * BCAP;
  int nb = bkt << 8;
  int vN = v * N;
  for (int i = tid; i < m; i += 256) {
    uint2 rec = bb[i];
    int src = rec.x & 0xFFFFu;
    int dl = (rec.x >> 16) & 0xFFu;
    float w = __uint_as_float(rec.y);
    int pos = atomicAdd(&lcnt[dl], 1);
    uint r4 = (uint)src | ((uint)__half_as_ushort(__float2half_rn(w)) << 16);
    if (pos < CAP) csr[((size_t)(vN + nb + dl)) * CAP + pos] = r4;
    atomicAdd(&lsum[dl], w);
  }
  __syncthreads();
  int node = nb + tid;
  if (node < N) {
    int deg = min(lcnt[tid], CAP);
    int dpad = min((deg + 7) & ~7, CAP);
    uint* __restrict__ row = csr + (size_t)(vN + node) * CAP;
    for (int i = deg; i < dpad; i++) row[i] = 0u;  // src=0, w=+0 (inert in conv1)
    cnt[vN + node] = deg;
    dinv1[vN + node] = rsqrtf(1.0f + lsum[tid]);
    dinv2[vN + node] = rsqrtf((float)(deg + 1));
  }
}

// ---------------- GEMM1 via MFMA, 3 branches fused (x read once) ------------
__global__ __launch_bounds__(256) void k_gemm1m(
    const float* __restrict__ x, const uint* __restrict__ wsw,
    const float* __restrict__ dinv1, uint* __restrict__ xwb, int N) {
  __shared__ float sc_all[4 * 16 * 64];  // 16 KB epilogue scratch (per-wave 4 KB)
  int wave = threadIdx.x >> 6, lane = threadIdx.x & 63;
  int n0 = blockIdx.x * 64 + wave * 16;
  int m = lane & 15, kq = lane >> 4;  // A: node m, k-group kq
  int arow = min(n0 + m, N - 1);
  const float* __restrict__ xr = x + (size_t)arow * FIN + kq * 8;
  ABfrag af[8];
#pragma unroll
  for (int ks = 0; ks < 8; ks++) {
    float4 a0 = *(const float4*)(xr + ks * 32);
    float4 a1 = *(const float4*)(xr + ks * 32 + 4);
    af[ks].u[0] = pack_bf16x2(a0.x, a0.y);
    af[ks].u[1] = pack_bf16x2(a0.z, a0.w);
    af[ks].u[2] = pack_bf16x2(a1.x, a1.y);
    af[ks].u[3] = pack_bf16x2(a1.z, a1.w);
  }
  float* sc = &sc_all[wave * 1024];  // 16x64 fp32 per wave
  int row2 = lane >> 2, cg = lane & 3;
  int node = n0 + row2;
#pragma unroll
  for (int v = 0; v < 3; v++) {
    int vN = v * N;
    f32x4 acc[4];
#pragma unroll
    for (int nt = 0; nt < 4; nt++) acc[nt] = (f32x4){0.f, 0.f, 0.f, 0.f};
    const uint* __restrict__ wv = wsw + v * 8192;
#pragma unroll
    for (int ks = 0; ks < 8; ks++) {
#pragma unroll
      for (int nt = 0; nt < 4; nt++) {
        ABfrag b;
        *(uint4*)b.u = *(const uint4*)&wv[(ks * 4 + nt) * 256 + lane * 4];
        acc[nt] = __builtin_amdgcn_mfma_f32_16x16x32_bf16(af[ks].v, b.v, acc[nt], 0, 0, 0);
      }
    }
    __syncthreads();  // epilogue scratch reuse boundary (prev v's reads done)
#pragma unroll
    for (int reg = 0; reg < 4; reg++) {
      int row = kq * 4 + reg;            // C/D: row=(lane>>4)*4+reg, col=lane&15
      float d1 = dinv1[vN + min(n0 + row, N - 1)];
#pragma unroll
      for (int nt = 0; nt < 4; nt++)
        sc[row * 64 + nt * 16 + m] = acc[nt][reg] * d1;
    }
    __syncthreads();
    const float4* sr = (const float4*)&sc[row2 * 64 + cg * 16];
    float4 c0 = sr[0], c1 = sr[1], c2 = sr[2], c3 = sr[3];
    uint4 o0, o1;
    o0.x = pack_bf16x2(c0.x, c0.y); o0.y = pack_bf16x2(c0.z, c0.w);
    o0.z = pack_bf16x2(c1.x, c1.y); o0.w = pack_bf16x2(c1.z, c1.w);
    o1.x = pack_bf16x2(c2.x, c2.y); o1.y = pack_bf16x2(c2.z, c2.w);
    o1.z = pack_bf16x2(c3.x, c3.y); o1.w = pack_bf16x2(c3.z, c3.w);
    if (node < N) {
      uint4* __restrict__ dst = (uint4*)(xwb + ((size_t)vN + node) * 32 + cg * 8);
      dst[0] = o0;
      dst[1] = o1;
    }
  }
}

// ---------------- conv1 pull: 2 nodes/wave, uniform 8-wide loop -------------
__global__ __launch_bounds__(256) void k_conv1(
    const uint* __restrict__ xwb, const uint* __restrict__ csr,
    const int* __restrict__ cnt,
    const float* __restrict__ dinv1, const float* __restrict__ dinv2,
    const float* __restrict__ b10, const float* __restrict__ b11, const float* __restrict__ b12,
    const float* __restrict__ W20, const float* __restrict__ W21, const float* __restrict__ W22,
    float* __restrict__ outf, float* __restrict__ g, int N) {
  int gt = blockIdx.x * 256 + threadIdx.x;
  int sub = gt & 31;
  int n = gt >> 5;
  if (n >= N) return;
  const float* b1s[3] = {b10, b11, b12};
  const float* W2s[3] = {W20, W21, W22};
  float fsum0 = 0.f, fsum1 = 0.f;
#pragma unroll
  for (int v = 0; v < 3; v++) {
    int vN = v * N;
    int nv = vN + n;
    const uint* __restrict__ row = csr + (size_t)nv * CAP;  // 256B-aligned
    int dpad = (cnt[nv] + 7) & ~7;   // rows zero-padded to multiple of 8 in p2
    float acc0 = 0.f, acc1 = 0.f;
    for (int i = 0; i < dpad; i += 8) {
      uint4 ra = *(const uint4*)(row + i);      // 16B-aligned
      uint4 rb = *(const uint4*)(row + i + 4);
      uint p0 = xwb[(size_t)(vN + (ra.x & 0xFFFFu)) * 32 + sub];
      uint p1 = xwb[(size_t)(vN + (ra.y & 0xFFFFu)) * 32 + sub];
      uint p2 = xwb[(size_t)(vN + (ra.z & 0xFFFFu)) * 32 + sub];
      uint p3 = xwb[(size_t)(vN + (ra.w & 0xFFFFu)) * 32 + sub];
      uint p4 = xwb[(size_t)(vN + (rb.x & 0xFFFFu)) * 32 + sub];
      uint p5 = xwb[(size_t)(vN + (rb.y & 0xFFFFu)) * 32 + sub];
      uint p6 = xwb[(size_t)(vN + (rb.z & 0xFFFFu)) * 32 + sub];
      uint p7 = xwb[(size_t)(vN + (rb.w & 0xFFFFu)) * 32 + sub];
      float w0 = rec_w(ra.x), w1 = rec_w(ra.y), w2 = rec_w(ra.z), w3 = rec_w(ra.w);
      float w4 = rec_w(rb.x), w5 = rec_w(rb.y), w6 = rec_w(rb.z), w7 = rec_w(rb.w);
      acc0 += w0 * __uint_as_float(p0 << 16);
      acc1 += w0 * __uint_as_float(p0 & 0xFFFF0000u);
      acc0 += w1 * __uint_as_float(p1 << 16);
      acc1 += w1 * __uint_as_float(p1 & 0xFFFF0000u);
      acc0 += w2 * __uint_as_float(p2 << 16);
      acc1 += w2 * __uint_as_float(p2 & 0xFFFF0000u);
      acc0 += w3 * __uint_as_float(p3 << 16);
      acc1 += w3 * __uint_as_float(p3 & 0xFFFF0000u);
      acc0 += w4 * __uint_as_float(p4 << 16);
      acc1 += w4 * __uint_as_float(p4 & 0xFFFF0000u);
      acc0 += w5 * __uint_as_float(p5 << 16);
      acc1 += w5 * __uint_as_float(p5 & 0xFFFF0000u);
      acc0 += w6 * __uint_as_float(p6 << 16);
      acc1 += w6 * __uint_as_float(p6 & 0xFFFF0000u);
      acc0 += w7 * __uint_as_float(p7 << 16);
      acc1 += w7 * __uint_as_float(p7 & 0xFFFF0000u);
    }
    uint ps = xwb[(size_t)nv * 32 + sub];  // self loop
    acc0 += __uint_as_float(ps << 16);
    acc1 += __uint_as_float(ps & 0xFFFF0000u);
    float d1 = dinv1[nv];
    float2 bb = ((const float2*)b1s[v])[sub];
    float h0 = fmaxf(d1 * acc0 + bb.x, 0.f);
    float h1 = fmaxf(d1 * acc1 + bb.y, 0.f);
    fsum0 += h0;
    fsum1 += h1;
    float2 ww = ((const float2*)W2s[v])[sub];
    float p = h0 * ww.x + h1 * ww.y;
#pragma unroll
    for (int off = 16; off > 0; off >>= 1) p += __shfl_down(p, off, 32);
    if (sub == 0) g[nv] = dinv2[nv] * p;
  }
  float2 fo;
  fo.x = fsum0;
  fo.y = fsum1;
  ((float2*)(outf + (size_t)n * NH))[sub] = fo;
}

// ---------------- conv2 pull: 16 lanes/node (true deg — ignores pads) -------
__global__ __launch_bounds__(256) void k_conv2(
    const uint* __restrict__ csr, const int* __restrict__ cnt,
    const float* __restrict__ dinv2, const float* __restrict__ g,
    const float* __restrict__ b20, const float* __restrict__ b21, const float* __restrict__ b22,
    float* __restrict__ outx, int N) {
  int gt = blockIdx.x * 256 + threadIdx.x;
  int l = gt & 15;
  int n = gt >> 4;
  if (n >= N) return;
  float tot = 0.f;
#pragma unroll
  for (int v = 0; v < 3; v++) {
    int vN = v * N;
    int nv = vN + n;
    const uint* __restrict__ row = csr + (size_t)nv * CAP;
    int deg = cnt[nv];
    float acc = 0.f;
    for (int i = l; i < deg; i += 16) acc += g[vN + (row[i] & 0xFFFFu)];
#pragma unroll
    for (int off = 1; off < 16; off <<= 1) acc += __shfl_xor(acc, off, 16);
    tot += dinv2[nv] * (acc + g[nv]);
  }
  if (l == 0) outx[n] = tot + b20[0] + b21[0] + b22[0];
}

extern "C" void kernel_launch(void* const* d_in, const int* in_sizes, int n_in,
                              void* d_out, int out_size, void* d_ws, size_t ws_size,
                              hipStream_t stream) {
  const float* x   = (const float*)d_in[0];
  const int*   ei0 = (const int*)d_in[1];
  const int*   ei1 = (const int*)d_in[2];
  const int*   ei2 = (const int*)d_in[3];
  const float* ew0 = (const float*)d_in[4];
  const float* ew1 = (const float*)d_in[5];
  const float* ew2 = (const float*)d_in[6];
  const float* W10 = (const float*)d_in[7];
  const float* b10 = (const float*)d_in[8];
  const float* W20 = (const float*)d_in[9];
  const float* b20 = (const float*)d_in[10];
  const float* W11 = (const float*)d_in[11];
  const float* b11 = (const float*)d_in[12];
  const float* W21 = (const float*)d_in[13];
  const float* b21 = (const float*)d_in[14];
  const float* W12 = (const float*)d_in[15];
  const float* b12 = (const float*)d_in[16];
  const float* W22 = (const float*)d_in[17];
  const float* b22 = (const float*)d_in[18];

  const int N = in_sizes[0] / FIN;  // 50000
  const int E = in_sizes[1] / 2;    // 800000
  const int n3 = 3 * N;

  char* p = (char*)d_ws;
  auto alloc = [&](size_t bytes) -> char* {
    char* r = p;
    p += (bytes + 255) & ~(size_t)255;
    return r;
  };
  // bbuf (pass1/2) and xwb (gemm1/conv1) are disjoint in time -> alias
  size_t xwb_bytes  = (size_t)n3 * 32 * sizeof(uint);               // 19.2 MB
  size_t bbuf_bytes = (size_t)3 * NBKT * BCAP * sizeof(uint2);      // 21.7 MB
  char*  shared_rgn = alloc(xwb_bytes > bbuf_bytes ? xwb_bytes : bbuf_bytes);
  uint*  xwb   = (uint*) shared_rgn;
  uint2* bbuf  = (uint2*)shared_rgn;
  uint*  csr   = (uint*) alloc((size_t)n3 * CAP * sizeof(uint));    // 38.4 MB
  uint*  wsw   = (uint*) alloc((size_t)3 * 8192 * sizeof(uint));    // 98 KB
  int*   bcnt  = (int*)  alloc((size_t)3 * NBKT * sizeof(int));
  int*   cnt   = (int*)  alloc((size_t)n3 * sizeof(int));
  float* dinv1 = (float*)alloc((size_t)n3 * sizeof(float));
  float* dinv2 = (float*)alloc((size_t)n3 * sizeof(float));
  float* g     = (float*)alloc((size_t)n3 * sizeof(float));
  (void)ws_size;

  float* outx = (float*)d_out;        // [N]
  float* outf = (float*)d_out + N;    // [N][64]

  k_wprep<<<dim3(3), 256, 0, stream>>>(W10, W11, W12, wsw, bcnt);
  k_p1<<<dim3((E + EPB - 1) / EPB, 3), 256, 0, stream>>>(ei0, ei1, ei2,
                                                         ew0, ew1, ew2, bcnt, bbuf, E);
  k_p2<<<dim3(NBKT, 3), 256, 0, stream>>>(bcnt, bbuf, cnt, csr, dinv1, dinv2, N);
  k_gemm1m<<<dim3((N + 63) / 64), 256, 0, stream>>>(x, wsw, dinv1, xwb, N);
  k_conv1<<<dim3((N * 32 + 255) / 256), 256, 0, stream>>>(
      xwb, csr, cnt, dinv1, dinv2, b10, b11, b12, W20, W21, W22, outf, g, N);
  k_conv2<<<dim3((N * 16 + 255) / 256), 256, 0, stream>>>(csr, cnt, dinv2, g,
                                                          b20, b21, b22, outx, N);
}